// Round 3
// baseline (77.139 us; speedup 1.0000x reference)
//
#include <hip/hip_runtime.h>
#include <cstddef>

#define T_DIM 30000
#define M_DIM 23
#define NJ    92
#define PADH  50
#define TILE  64      // output timesteps per conv block
#define STR   184     // Yt stride in bf16 units (368 B = 92 dw, 92%32=28 -> even bank spread)
#define WKP   128     // padded weight length in LDS, index = h + 7

__device__ __forceinline__ unsigned short f2bf(float f) {
    unsigned int u = __float_as_uint(f);
    return (unsigned short)((u + 0x7fffu + ((u >> 16) & 1u)) >> 16);
}
__device__ __forceinline__ float bflo(unsigned int u) { return __uint_as_float(u << 16); }
__device__ __forceinline__ float bfhi(unsigned int u) { return __uint_as_float(u & 0xffff0000u); }

// ---- Kernel B: X (T,1500) fp32 -> Yb (T,92) bf16 ; Yb[t,j] = sum_{n%92==j} X[t,n]
__global__ __launch_bounds__(256) void reduce_k(const float* __restrict__ X,
                                                unsigned short* __restrict__ Yb) {
    int idx = blockIdx.x * 256 + threadIdx.x;
    if (idx >= T_DIM * 23) return;
    int t = idx / 23;
    int q = idx - t * 23;                     // float4-column class 0..22
    const float4* Xr = reinterpret_cast<const float4*>(X) + (size_t)t * 375;
    float4 s = make_float4(0.f, 0.f, 0.f, 0.f);
    int kc = (q < 7) ? 17 : 16;               // 7*17 + 16*16 = 375
    for (int k = 0; k < kc; ++k) {
        float4 v = Xr[q + 23 * k];
        s.x += v.x; s.y += v.y; s.z += v.z; s.w += v.w;
    }
    ushort4 o;
    o.x = f2bf(s.x); o.y = f2bf(s.y); o.z = f2bf(s.z); o.w = f2bf(s.w);
    reinterpret_cast<ushort4*>(Yb)[(size_t)t * 23 + q] = o;
}

// ---- Kernel C: depthwise temporal conv (92 chans, 4 kernels) + tree cascade
// 768 threads: compute split as (m 0..22) x (i8 0..7) x (g 0..3) = 736 active.
__global__ __launch_bounds__(768) void conv_tree_k(
    const unsigned short* __restrict__ Yb,
    const float* __restrict__ Vo,
    const float* __restrict__ Tau,
    const float* __restrict__ Delta,
    const float* __restrict__ W,
    const float* __restrict__ C,
    const float* __restrict__ Theta,
    float* __restrict__ out)
{
    // arena: phase 1 = Yt (92 cols x 184 bf16, col-major) ; phase 2 = partials P[64][23][4] f32
    __shared__ __align__(16) unsigned char arena[NJ * STR * 2];   // 33856 B
    __shared__ __align__(16) float wkp2[4 * WKP];                 // 2 KB
    __shared__ __align__(16) float sub[TILE * 24];                // 6.1 KB
    __shared__ float sTheta[M_DIM];
    __shared__ float sExpC[M_DIM];

    unsigned short* Yt = reinterpret_cast<unsigned short*>(arena);
    float*          P  = reinterpret_cast<float*>(arena);

    const int tid = threadIdx.x;
    const int t0  = blockIdx.x * TILE;

    // --- weights into LDS: wkp2[g][i] = wk(g, h=i-7) * W[g], zero outside h in [0,100]
    float eD = __expf(Delta[0]);
    if (tid < 4 * WKP) {
        int g = tid >> 7, hp = tid & 127;
        int h = hp - 7;
        float val = 0.f;
        if (h >= 0 && h <= 100) {
            float tt  = fmaxf((float)h - eD, 0.f);
            float tau = __expf(Tau[g]);
            float tf  = tt / tau;
            float fast = tf * __expf(-tf);
            float kv;
            if (g < 2) {
                float ts   = tt / (tau * 2.8f + 10.4f);
                float slow = ts * __expf(-ts) * 0.3f;
                kv = (fast + slow) * (1.0f / 1.3f);
            } else {
                kv = fast;
            }
            val = kv * W[g];
        }
        wkp2[tid] = val;
    }
    if (tid < M_DIM) {
        sTheta[tid] = Theta[tid];
        sExpC[tid]  = __expf(C[tid]);
    }

    // --- stage Yb rows [t0-50, t0+118) transposed into Yt[col'][t'] (bf16),
    //     col' = (c>>2) + 23*(c&3); row pairs packed into dwords.
    {
        unsigned int* Yw = reinterpret_cast<unsigned int*>(Yt);
        for (int i = tid; i < 84 * 23; i += 768) {
            int rp = i / 23;
            int q  = i - rp * 23;
            int g0 = t0 - PADH + 2 * rp;
            ushort4 ra = make_ushort4(0, 0, 0, 0);
            ushort4 rb = make_ushort4(0, 0, 0, 0);
            if ((unsigned)g0       < (unsigned)T_DIM) ra = reinterpret_cast<const ushort4*>(Yb)[(size_t)g0 * 23 + q];
            if ((unsigned)(g0 + 1) < (unsigned)T_DIM) rb = reinterpret_cast<const ushort4*>(Yb)[(size_t)(g0 + 1) * 23 + q];
            Yw[(q     ) * 92 + rp] = (unsigned)ra.x | ((unsigned)rb.x << 16);
            Yw[(q + 23) * 92 + rp] = (unsigned)ra.y | ((unsigned)rb.y << 16);
            Yw[(q + 46) * 92 + rp] = (unsigned)ra.z | ((unsigned)rb.z << 16);
            Yw[(q + 69) * 92 + rp] = (unsigned)ra.w | ((unsigned)rb.w << 16);
        }
    }
    __syncthreads();

    // --- compute: thread = (g, m, i8); weights for this g held in registers
    float acc[8];
    int m = 0, i8 = 0, g = 0;
    if (tid < 736) {
        g = tid & 3;
        int mi = tid >> 2;          // 0..183
        m  = mi % 23;
        i8 = mi / 23;

        // full padded weight vector for this g -> registers (statically indexed)
        float w[120];
        {
            const float4* wsrc = reinterpret_cast<const float4*>(&wkp2[g * WKP]);
            #pragma unroll
            for (int i = 0; i < 30; ++i) {
                float4 t4 = wsrc[i];
                w[4*i] = t4.x; w[4*i+1] = t4.y; w[4*i+2] = t4.z; w[4*i+3] = t4.w;
            }
        }

        // permuted LDS column for (m, g): j = m + 23a with j%4 == g -> col' = (j>>2) + 23g
        int a  = (3 * ((g - m + 8) & 3)) & 3;
        int j  = m + 23 * a;
        int jc = (j >> 2) + 23 * g;
        const unsigned short* colp = &Yt[jc * STR];

        #pragma unroll
        for (int r = 0; r < 8; ++r) acc[r] = 0.f;

        const int base = i8 * 8;
        #pragma unroll
        for (int rb = 0; rb < 112; rb += 8) {
            uint4 vv = *reinterpret_cast<const uint4*>(&colp[base + rb]);
            float v[8];
            v[0] = bflo(vv.x); v[1] = bfhi(vv.x);
            v[2] = bflo(vv.y); v[3] = bfhi(vv.y);
            v[4] = bflo(vv.z); v[5] = bfhi(vv.z);
            v[6] = bflo(vv.w); v[7] = bfhi(vv.w);
            #pragma unroll
            for (int k = 0; k < 8; ++k) {
                #pragma unroll
                for (int r = 0; r < 8; ++r)
                    acc[r] += v[k] * w[rb + k - r + 7];
            }
        }
    }
    __syncthreads();   // Yt reads done; arena becomes partials P[t'][m][g]

    if (tid < 736) {
        #pragma unroll
        for (int r = 0; r < 8; ++r)
            P[(i8 * 8 + r) * 92 + m * 4 + g] = acc[r];
    }
    __syncthreads();

    // --- reduce over g: sub[t'][m] = sum_g P[t'][m][g]
    for (int p = tid; p < TILE * 23; p += 768) {
        int t  = p / 23;
        int mm = p - t * 23;
        float4 v4 = *reinterpret_cast<const float4*>(&P[t * 92 + mm * 4]);
        sub[t * 24 + mm] = v4.x + v4.y + v4.z + v4.w;
    }
    __syncthreads();

    // --- tree cascade, one thread per timestep
    if (tid < TILE) {
        int t = t0 + tid;
        if (t < T_DIM) {
            const float* s = &sub[tid * 24];
            float o[M_DIM];
            #pragma unroll
            for (int mm = 11; mm < 23; ++mm) {
                float x = s[mm] - sTheta[mm];
                o[mm] = sExpC[mm] / (1.f + __expf(-x));
            }
            #pragma unroll
            for (int r = 10; r >= 0; --r) {
                float x = s[r] + o[2 * r + 1] + o[2 * r + 2] - sTheta[r];
                o[r] = sExpC[r] / (1.f + __expf(-x));
            }
            out[t] = o[0] + Vo[0];
        }
    }
}

extern "C" void kernel_launch(void* const* d_in, const int* in_sizes, int n_in,
                              void* d_out, int out_size, void* d_ws, size_t ws_size,
                              hipStream_t stream) {
    const float* X     = (const float*)d_in[0];
    const float* Vo    = (const float*)d_in[1];
    const float* Tau   = (const float*)d_in[2];
    const float* Delta = (const float*)d_in[3];
    const float* W     = (const float*)d_in[4];
    const float* C     = (const float*)d_in[5];
    const float* Theta = (const float*)d_in[6];
    float* out = (float*)d_out;
    unsigned short* Yb = (unsigned short*)d_ws;   // T_DIM * 92 bf16 = 5.52 MB

    reduce_k<<<(T_DIM * 23 + 255) / 256, 256, 0, stream>>>(X, Yb);
    conv_tree_k<<<(T_DIM + TILE - 1) / TILE, 768, 0, stream>>>(
        Yb, Vo, Tau, Delta, W, C, Theta, out);
}

// Round 4
// 75.036 us; speedup vs baseline: 1.0280x; 1.0280x over previous
//
#include <hip/hip_runtime.h>
#include <cstddef>

#define T_DIM 30000
#define M_DIM 23
#define NJ    92
#define PADH  50
#define TILE  64      // output timesteps per conv block
#define STR   184     // Yt stride in bf16 units (368 B; 92 dwords, 92%32=28 -> spread banks)
#define WKP   128     // padded weight length, index = h + 7

__device__ __forceinline__ unsigned short f2bf(float f) {
    unsigned int u = __float_as_uint(f);
    return (unsigned short)((u + 0x7fffu + ((u >> 16) & 1u)) >> 16);
}
__device__ __forceinline__ float bflo(unsigned int u) { return __uint_as_float(u << 16); }
__device__ __forceinline__ float bfhi(unsigned int u) { return __uint_as_float(u & 0xffff0000u); }

// ---- Kernel A: weight table wtab[g*128 + h+7] = wk(g,h) * W[g], zero-padded
__global__ __launch_bounds__(512) void wtab_k(const float* __restrict__ Tau,
                                              const float* __restrict__ Delta,
                                              const float* __restrict__ W,
                                              float* __restrict__ wtab) {
    int i = threadIdx.x;                      // 0..511
    int g = i >> 7, hp = i & 127, h = hp - 7;
    float val = 0.f;
    if (h >= 0 && h <= 100) {
        float eD  = __expf(Delta[0]);
        float tt  = fmaxf((float)h - eD, 0.f);
        float tau = __expf(Tau[g]);
        float tf  = tt / tau;
        float fast = tf * __expf(-tf);
        float kv;
        if (g < 2) {
            float ts   = tt / (tau * 2.8f + 10.4f);
            float slow = ts * __expf(-ts) * 0.3f;
            kv = (fast + slow) * (1.0f / 1.3f);
        } else {
            kv = fast;
        }
        val = kv * W[g];
    }
    wtab[i] = val;
}

// ---- Kernel B: X (T,1500) fp32 -> Yb (T,92) bf16 ; Yb[t,j] = sum_{n%92==j} X[t,n]
__global__ __launch_bounds__(256) void reduce_k(const float* __restrict__ X,
                                                unsigned short* __restrict__ Yb) {
    int idx = blockIdx.x * 256 + threadIdx.x;
    if (idx >= T_DIM * 23) return;
    int t = idx / 23;
    int q = idx - t * 23;
    const float4* Xr = reinterpret_cast<const float4*>(X) + (size_t)t * 375;
    float4 s = make_float4(0.f, 0.f, 0.f, 0.f);
    int kc = (q < 7) ? 17 : 16;               // 7*17 + 16*16 = 375
    for (int k = 0; k < kc; ++k) {
        float4 v = Xr[q + 23 * k];
        s.x += v.x; s.y += v.y; s.z += v.z; s.w += v.w;
    }
    ushort4 o;
    o.x = f2bf(s.x); o.y = f2bf(s.y); o.z = f2bf(s.z); o.w = f2bf(s.w);
    reinterpret_cast<ushort4*>(Yb)[(size_t)t * 23 + q] = o;
}

// ---- Kernel C: depthwise temporal conv (92 chans, 4 kernels) + tree cascade
// 768 threads; g = tid/192 is WAVE-UNIFORM -> weights via scalar loads (SGPRs).
__global__ __launch_bounds__(768) void conv_tree_k(
    const unsigned short* __restrict__ Yb,
    const float* __restrict__ wtab,
    const float* __restrict__ Vo,
    const float* __restrict__ C,
    const float* __restrict__ Theta,
    float* __restrict__ out)
{
    // arena: phase 1 = Yt (92 cols x 184 bf16, col-major); phase 2 = P[64][92] f32
    __shared__ __align__(16) unsigned char arena[NJ * STR * 2];   // 33856 B
    __shared__ __align__(16) float sub[TILE * 24];                // 6144 B
    __shared__ float sTheta[M_DIM];
    __shared__ float sExpC[M_DIM];

    unsigned short* Yt = reinterpret_cast<unsigned short*>(arena);
    float*          P  = reinterpret_cast<float*>(arena);

    const int tid = threadIdx.x;
    const int t0  = blockIdx.x * TILE;

    if (tid < M_DIM) {
        sTheta[tid] = Theta[tid];
        sExpC[tid]  = __expf(C[tid]);
    }

    // --- stage Yb rows [t0-50, t0+118) transposed into Yt[col'][t'] (bf16),
    //     col' = (c>>2) + 23*(c&3); row pairs packed into dwords.
    {
        unsigned int* Yw = reinterpret_cast<unsigned int*>(Yt);
        for (int i = tid; i < 84 * 23; i += 768) {
            int rp = i / 23;
            int q  = i - rp * 23;
            int g0 = t0 - PADH + 2 * rp;
            ushort4 ra = make_ushort4(0, 0, 0, 0);
            ushort4 rb = make_ushort4(0, 0, 0, 0);
            if ((unsigned)g0       < (unsigned)T_DIM) ra = reinterpret_cast<const ushort4*>(Yb)[(size_t)g0 * 23 + q];
            if ((unsigned)(g0 + 1) < (unsigned)T_DIM) rb = reinterpret_cast<const ushort4*>(Yb)[(size_t)(g0 + 1) * 23 + q];
            Yw[(q     ) * 92 + rp] = (unsigned)ra.x | ((unsigned)rb.x << 16);
            Yw[(q + 23) * 92 + rp] = (unsigned)ra.y | ((unsigned)rb.y << 16);
            Yw[(q + 46) * 92 + rp] = (unsigned)ra.z | ((unsigned)rb.z << 16);
            Yw[(q + 69) * 92 + rp] = (unsigned)ra.w | ((unsigned)rb.w << 16);
        }
    }
    __syncthreads();

    // --- compute: g = tid/192 (wave-uniform); r = (m, i8) within the g-group
    int gq = tid / 192;
    gq = __builtin_amdgcn_readfirstlane(gq);          // assert wave-uniform -> SGPR
    const float* __restrict__ wg = wtab + gq * WKP;   // scalar base
    int r  = tid - gq * 192;

    float acc[8];
    int m = 0, i8 = 0;
    if (r < 184) {
        m  = r % 23;
        i8 = r / 23;
        // column j = m + 23a with j%4 == gq  ->  permuted col' = (j>>2) + 23*gq
        int a  = (3 * ((gq - m + 8) & 3)) & 3;
        int j  = m + 23 * a;
        int jc = (j >> 2) + 23 * gq;
        const unsigned short* colp = &Yt[jc * STR];

        #pragma unroll
        for (int rr = 0; rr < 8; ++rr) acc[rr] = 0.f;

        const int base = i8 * 8;
        #pragma unroll
        for (int rb = 0; rb < 112; rb += 8) {
            uint4 vv = *reinterpret_cast<const uint4*>(&colp[base + rb]);
            float v[8];
            v[0] = bflo(vv.x); v[1] = bfhi(vv.x);
            v[2] = bflo(vv.y); v[3] = bfhi(vv.y);
            v[4] = bflo(vv.z); v[5] = bfhi(vv.z);
            v[6] = bflo(vv.w); v[7] = bfhi(vv.w);
            #pragma unroll
            for (int k = 0; k < 8; ++k) {
                #pragma unroll
                for (int rr = 0; rr < 8; ++rr)
                    acc[rr] += v[k] * wg[rb + k - rr + 7];   // scalar operand
            }
        }
    }
    __syncthreads();   // Yt reads done; arena becomes partials P[t'][m*4+g]

    if (r < 184) {
        #pragma unroll
        for (int rr = 0; rr < 8; ++rr)
            P[(i8 * 8 + rr) * 92 + m * 4 + gq] = acc[rr];
    }
    __syncthreads();

    // --- reduce over g: sub[t'][m] = sum_g P[t'][m][g]
    for (int p = tid; p < TILE * 23; p += 768) {
        int t  = p / 23;
        int mm = p - t * 23;
        float4 v4 = *reinterpret_cast<const float4*>(&P[t * 92 + mm * 4]);
        sub[t * 24 + mm] = v4.x + v4.y + v4.z + v4.w;
    }
    __syncthreads();

    // --- tree cascade, one thread per timestep
    if (tid < TILE) {
        int t = t0 + tid;
        if (t < T_DIM) {
            const float* s = &sub[tid * 24];
            float o[M_DIM];
            #pragma unroll
            for (int mm = 11; mm < 23; ++mm) {
                float x = s[mm] - sTheta[mm];
                o[mm] = sExpC[mm] / (1.f + __expf(-x));
            }
            #pragma unroll
            for (int rr = 10; rr >= 0; --rr) {
                float x = s[rr] + o[2 * rr + 1] + o[2 * rr + 2] - sTheta[rr];
                o[rr] = sExpC[rr] / (1.f + __expf(-x));
            }
            out[t] = o[0] + Vo[0];
        }
    }
}

extern "C" void kernel_launch(void* const* d_in, const int* in_sizes, int n_in,
                              void* d_out, int out_size, void* d_ws, size_t ws_size,
                              hipStream_t stream) {
    const float* X     = (const float*)d_in[0];
    const float* Vo    = (const float*)d_in[1];
    const float* Tau   = (const float*)d_in[2];
    const float* Delta = (const float*)d_in[3];
    const float* W     = (const float*)d_in[4];
    const float* C     = (const float*)d_in[5];
    const float* Theta = (const float*)d_in[6];
    float* out = (float*)d_out;

    unsigned short* Yb = (unsigned short*)d_ws;                   // 5.52 MB
    float* wtab = (float*)((char*)d_ws + (size_t)T_DIM * NJ * 2); // 4*128 floats

    wtab_k<<<1, 512, 0, stream>>>(Tau, Delta, W, wtab);
    reduce_k<<<(T_DIM * 23 + 255) / 256, 256, 0, stream>>>(X, Yb);
    conv_tree_k<<<(T_DIM + TILE - 1) / TILE, 768, 0, stream>>>(
        Yb, wtab, Vo, C, Theta, out);
}

// Round 5
// 57.301 us; speedup vs baseline: 1.3462x; 1.3095x over previous
//
#include <hip/hip_runtime.h>
#include <cstddef>

#define T_DIM 30000
#define M_DIM 23
#define NJ    92
#define PADH  50
#define TILE  64      // output timesteps per conv block
#define STR   184     // Yt stride in bf16 units (368 B)
#define WKP   128     // padded weight length, index = h + 7
#define RROWS 8       // rows per reduce block
#define XP4   377     // LDS pitch in float4 (uniform bank spread: 1508 dw % 32 = 4)

__device__ __forceinline__ unsigned short f2bf(float f) {
    unsigned int u = __float_as_uint(f);
    return (unsigned short)((u + 0x7fffu + ((u >> 16) & 1u)) >> 16);
}
__device__ __forceinline__ float bflo(unsigned int u) { return __uint_as_float(u << 16); }
__device__ __forceinline__ float bfhi(unsigned int u) { return __uint_as_float(u & 0xffff0000u); }

// ---- Kernel B: X (T,1500) fp32 -> Yb (T,92) bf16 ; Yb[t,j] = sum_{n%92==j} X[t,n]
// LDS-transpose: global reads are pure-contiguous float4; strided reads hit LDS.
__global__ __launch_bounds__(256) void reduce_k(const float* __restrict__ X,
                                                unsigned short* __restrict__ Yb) {
    __shared__ __align__(16) float4 Xs[RROWS * XP4];   // 48256 B

    const int tid = threadIdx.x;
    const int tb  = blockIdx.x * RROWS;

    // phase A: stage 8 rows (3000 float4, contiguous) into LDS with padded pitch
    const float4* Xg = reinterpret_cast<const float4*>(X) + (size_t)tb * 375;
    #pragma unroll
    for (int it = 0; it < 12; ++it) {
        int i = tid + 256 * it;
        if (i < 3000) {
            int r = i / 375;
            int pos = i - r * 375;
            Xs[r * XP4 + pos] = Xg[i];
        }
    }
    __syncthreads();

    // phase B: thread (r,q) sums float4s at pos = q + 23k  (k < 17 if q<7 else 16)
    if (tid < 184) {
        int r = tid / 23;
        int q = tid - 23 * r;
        const float4* row = &Xs[r * XP4];
        float4 s = make_float4(0.f, 0.f, 0.f, 0.f);
        #pragma unroll
        for (int k = 0; k < 16; ++k) {
            float4 v = row[q + 23 * k];
            s.x += v.x; s.y += v.y; s.z += v.z; s.w += v.w;
        }
        if (q < 7) {
            float4 v = row[q + 23 * 16];
            s.x += v.x; s.y += v.y; s.z += v.z; s.w += v.w;
        }
        ushort4 o;
        o.x = f2bf(s.x); o.y = f2bf(s.y); o.z = f2bf(s.z); o.w = f2bf(s.w);
        reinterpret_cast<ushort4*>(Yb)[(size_t)(tb + r) * 23 + q] = o;
    }
}

// ---- Kernel C: depthwise temporal conv (92 chans, 4 kernels) + tree cascade
// (exact round-2 structure: 192 threads, LDS weights, b128 column reads)
__global__ __launch_bounds__(192) void conv_tree_k(
    const unsigned short* __restrict__ Yb,
    const float* __restrict__ Vo,
    const float* __restrict__ Tau,
    const float* __restrict__ Delta,
    const float* __restrict__ W,
    const float* __restrict__ C,
    const float* __restrict__ Theta,
    float* __restrict__ out)
{
    __shared__ __align__(16) unsigned short Yt[NJ * STR];  // col-major bf16, 33.9 KB
    __shared__ __align__(16) float wkp2[4 * WKP];          // zero-padded weights, 2 KB
    __shared__ float sub[TILE * 24];                       // 6.1 KB
    __shared__ float sTheta[M_DIM];
    __shared__ float sExpC[M_DIM];

    const int tid = threadIdx.x;
    const int t0  = blockIdx.x * TILE;

    // --- weights: wkp2[g][i] = wk(g, h=i-7) * W[g], zero outside h in [0,100]
    float eD = __expf(Delta[0]);
    for (int i = tid; i < 4 * WKP; i += 192) {
        int g = i >> 7, hp = i & 127;
        int h = hp - 7;
        float val = 0.f;
        if (h >= 0 && h <= 100) {
            float tt  = fmaxf((float)h - eD, 0.f);
            float tau = __expf(Tau[g]);
            float tf  = tt / tau;
            float fast = tf * __expf(-tf);
            float kv;
            if (g < 2) {
                float ts   = tt / (tau * 2.8f + 10.4f);
                float slow = ts * __expf(-ts) * 0.3f;
                kv = (fast + slow) * (1.0f / 1.3f);
            } else {
                kv = fast;
            }
            val = kv * W[g];
        }
        wkp2[i] = val;
    }
    if (tid < M_DIM) {
        sTheta[tid] = Theta[tid];
        sExpC[tid]  = __expf(C[tid]);
    }

    // --- stage Yb rows [t0-50, t0+118) transposed into Yt[col'][t'] (bf16),
    //     col' = (c>>2) + 23*(c&3); row pairs packed into dwords.
    {
        unsigned int* Yw = reinterpret_cast<unsigned int*>(Yt);
        for (int i = tid; i < 84 * 23; i += 192) {
            int rp = i / 23;
            int q  = i - rp * 23;
            int g0 = t0 - PADH + 2 * rp;
            ushort4 ra = make_ushort4(0, 0, 0, 0);
            ushort4 rb = make_ushort4(0, 0, 0, 0);
            if ((unsigned)g0       < (unsigned)T_DIM) ra = reinterpret_cast<const ushort4*>(Yb)[(size_t)g0 * 23 + q];
            if ((unsigned)(g0 + 1) < (unsigned)T_DIM) rb = reinterpret_cast<const ushort4*>(Yb)[(size_t)(g0 + 1) * 23 + q];
            Yw[(q     ) * 92 + rp] = (unsigned)ra.x | ((unsigned)rb.x << 16);
            Yw[(q + 23) * 92 + rp] = (unsigned)ra.y | ((unsigned)rb.y << 16);
            Yw[(q + 46) * 92 + rp] = (unsigned)ra.z | ((unsigned)rb.z << 16);
            Yw[(q + 69) * 92 + rp] = (unsigned)ra.w | ((unsigned)rb.w << 16);
        }
    }
    __syncthreads();

    // --- compute: 184 threads = 23 m x 8 t-subblocks of 8 outputs
    int m = 0, i8 = 0;
    float acc[8];
    if (tid < 184) {
        m  = tid % 23;
        i8 = tid / 23;
        int jcol[4];
        #pragma unroll
        for (int a = 0; a < 4; ++a) {
            int j = m + 23 * a;
            int g = j & 3;
            jcol[g] = (j >> 2) + 23 * g;      // permuted column for (m,g)
        }
        #pragma unroll
        for (int r = 0; r < 8; ++r) acc[r] = 0.f;

        const int base = i8 * 8;
        for (int rb = 0; rb < 112; rb += 8) {
            #pragma unroll
            for (int g = 0; g < 4; ++g) {
                uint4 vv = *reinterpret_cast<const uint4*>(&Yt[jcol[g] * STR + base + rb]);
                float v[8];
                v[0] = bflo(vv.x); v[1] = bfhi(vv.x);
                v[2] = bflo(vv.y); v[3] = bfhi(vv.y);
                v[4] = bflo(vv.z); v[5] = bfhi(vv.z);
                v[6] = bflo(vv.w); v[7] = bfhi(vv.w);
                const float4* wp = reinterpret_cast<const float4*>(&wkp2[g * WKP + rb]);
                float4 w0 = wp[0], w1 = wp[1], w2 = wp[2], w3 = wp[3];
                float wf[16] = { w0.x, w0.y, w0.z, w0.w, w1.x, w1.y, w1.z, w1.w,
                                 w2.x, w2.y, w2.z, w2.w, w3.x, w3.y, w3.z, w3.w };
                #pragma unroll
                for (int k = 0; k < 8; ++k) {
                    #pragma unroll
                    for (int r = 0; r < 8; ++r)
                        acc[r] += v[k] * wf[k - r + 7];
                }
            }
        }
        #pragma unroll
        for (int r = 0; r < 8; ++r)
            sub[(base + r) * 24 + m] = acc[r];
    }
    __syncthreads();

    // --- tree cascade, one thread per timestep
    if (tid < TILE) {
        int t = t0 + tid;
        if (t < T_DIM) {
            const float* s = &sub[tid * 24];
            float o[M_DIM];
            #pragma unroll
            for (int mm = 11; mm < 23; ++mm) {
                float x = s[mm] - sTheta[mm];
                o[mm] = sExpC[mm] / (1.f + __expf(-x));
            }
            #pragma unroll
            for (int r = 10; r >= 0; --r) {
                float x = s[r] + o[2 * r + 1] + o[2 * r + 2] - sTheta[r];
                o[r] = sExpC[r] / (1.f + __expf(-x));
            }
            out[t] = o[0] + Vo[0];
        }
    }
}

extern "C" void kernel_launch(void* const* d_in, const int* in_sizes, int n_in,
                              void* d_out, int out_size, void* d_ws, size_t ws_size,
                              hipStream_t stream) {
    const float* X     = (const float*)d_in[0];
    const float* Vo    = (const float*)d_in[1];
    const float* Tau   = (const float*)d_in[2];
    const float* Delta = (const float*)d_in[3];
    const float* W     = (const float*)d_in[4];
    const float* C     = (const float*)d_in[5];
    const float* Theta = (const float*)d_in[6];
    float* out = (float*)d_out;
    unsigned short* Yb = (unsigned short*)d_ws;   // T_DIM * 92 bf16 = 5.52 MB

    reduce_k<<<T_DIM / RROWS, 256, 0, stream>>>(X, Yb);
    conv_tree_k<<<(T_DIM + TILE - 1) / TILE, 192, 0, stream>>>(
        Yb, Vo, Tau, Delta, W, C, Theta, out);
}

// Round 6
// 51.196 us; speedup vs baseline: 1.5067x; 1.1193x over previous
//
#include <hip/hip_runtime.h>
#include <cstddef>

#define T_DIM 30000
#define M_DIM 23
#define NJ    92
#define PADH  50
#define TILE  64      // output timesteps per conv block
#define STR   184     // Yt stride in bf16 units (368 B = 23*16 -> b128-aligned columns)
#define WKP   128     // padded weight length, index = h + 7
#define RROWS 8       // rows per reduce block
#define XP4   377     // reduce LDS pitch in float4

__device__ __forceinline__ unsigned short f2bf(float f) {
    unsigned int u = __float_as_uint(f);
    return (unsigned short)((u + 0x7fffu + ((u >> 16) & 1u)) >> 16);
}
__device__ __forceinline__ float bflo(unsigned int u) { return __uint_as_float(u << 16); }
__device__ __forceinline__ float bfhi(unsigned int u) { return __uint_as_float(u & 0xffff0000u); }

// ---- Kernel B: X (T,1500) fp32 -> Yb (T,92) bf16 ; Yb[t,j] = sum_{n%92==j} X[t,n]
// LDS-transpose: global reads pure-contiguous float4; strided reads hit LDS.
__global__ __launch_bounds__(256) void reduce_k(const float* __restrict__ X,
                                                unsigned short* __restrict__ Yb) {
    __shared__ __align__(16) float4 Xs[RROWS * XP4];   // 48256 B

    const int tid = threadIdx.x;
    const int tb  = blockIdx.x * RROWS;

    const float4* Xg = reinterpret_cast<const float4*>(X) + (size_t)tb * 375;
    #pragma unroll
    for (int it = 0; it < 12; ++it) {
        int i = tid + 256 * it;
        if (i < 3000) {
            int r = i / 375;
            int pos = i - r * 375;
            Xs[r * XP4 + pos] = Xg[i];
        }
    }
    __syncthreads();

    if (tid < 184) {
        int r = tid / 23;
        int q = tid - 23 * r;
        const float4* row = &Xs[r * XP4];
        float4 s = make_float4(0.f, 0.f, 0.f, 0.f);
        #pragma unroll
        for (int k = 0; k < 16; ++k) {
            float4 v = row[q + 23 * k];
            s.x += v.x; s.y += v.y; s.z += v.z; s.w += v.w;
        }
        if (q < 7) {
            float4 v = row[q + 23 * 16];
            s.x += v.x; s.y += v.y; s.z += v.z; s.w += v.w;
        }
        ushort4 o;
        o.x = f2bf(s.x); o.y = f2bf(s.y); o.z = f2bf(s.z); o.w = f2bf(s.w);
        reinterpret_cast<ushort4*>(Yb)[(size_t)(tb + r) * 23 + q] = o;
    }
}

// ---- Kernel C: depthwise temporal conv (92 chans, 4 kernels) + tree cascade
// 768 threads; g = tid/192 is wave-uniform. Each thread computes one g-partial
// with the round-2 inner loop (LDS vector weights, b128 column reads).
__global__ __launch_bounds__(768) void conv_tree_k(
    const unsigned short* __restrict__ Yb,
    const float* __restrict__ Vo,
    const float* __restrict__ Tau,
    const float* __restrict__ Delta,
    const float* __restrict__ W,
    const float* __restrict__ C,
    const float* __restrict__ Theta,
    float* __restrict__ out)
{
    // arena: phase 1 = Yt[92][184] bf16 col-major (33856 B); phase 2 = P[64][92] f32 (23552 B)
    __shared__ __align__(16) unsigned char arena[NJ * STR * 2];
    __shared__ __align__(16) float wkp2[4 * WKP];          // zero-padded weights, 2 KB
    __shared__ __align__(16) float sub[TILE * 24];         // 6.1 KB
    __shared__ float sTheta[M_DIM];
    __shared__ float sExpC[M_DIM];

    unsigned short* Yt = reinterpret_cast<unsigned short*>(arena);
    float*          P  = reinterpret_cast<float*>(arena);

    const int tid = threadIdx.x;
    const int t0  = blockIdx.x * TILE;

    // --- weights: wkp2[g][i] = wk(g, h=i-7) * W[g], zero outside h in [0,100]
    if (tid < 4 * WKP) {
        int g = tid >> 7, hp = tid & 127;
        int h = hp - 7;
        float val = 0.f;
        if (h >= 0 && h <= 100) {
            float eD  = __expf(Delta[0]);
            float tt  = fmaxf((float)h - eD, 0.f);
            float tau = __expf(Tau[g]);
            float tf  = tt / tau;
            float fast = tf * __expf(-tf);
            float kv;
            if (g < 2) {
                float ts   = tt / (tau * 2.8f + 10.4f);
                float slow = ts * __expf(-ts) * 0.3f;
                kv = (fast + slow) * (1.0f / 1.3f);
            } else {
                kv = fast;
            }
            val = kv * W[g];
        }
        wkp2[tid] = val;
    }
    if (tid < M_DIM) {
        sTheta[tid] = Theta[tid];
        sExpC[tid]  = __expf(C[tid]);
    }

    // --- stage Yb rows [t0-50, t0+118) transposed into Yt[col'][t'] (bf16),
    //     col' = (c>>2) + 23*(c&3); row pairs packed into dwords.
    {
        unsigned int* Yw = reinterpret_cast<unsigned int*>(Yt);
        for (int i = tid; i < 84 * 23; i += 768) {
            int rp = i / 23;
            int q  = i - rp * 23;
            int g0 = t0 - PADH + 2 * rp;
            ushort4 ra = make_ushort4(0, 0, 0, 0);
            ushort4 rb4 = make_ushort4(0, 0, 0, 0);
            if ((unsigned)g0       < (unsigned)T_DIM) ra  = reinterpret_cast<const ushort4*>(Yb)[(size_t)g0 * 23 + q];
            if ((unsigned)(g0 + 1) < (unsigned)T_DIM) rb4 = reinterpret_cast<const ushort4*>(Yb)[(size_t)(g0 + 1) * 23 + q];
            Yw[(q     ) * 92 + rp] = (unsigned)ra.x | ((unsigned)rb4.x << 16);
            Yw[(q + 23) * 92 + rp] = (unsigned)ra.y | ((unsigned)rb4.y << 16);
            Yw[(q + 46) * 92 + rp] = (unsigned)ra.z | ((unsigned)rb4.z << 16);
            Yw[(q + 69) * 92 + rp] = (unsigned)ra.w | ((unsigned)rb4.w << 16);
        }
    }
    __syncthreads();

    // --- compute: g = tid/192 (wave-uniform, 3 waves per g); r = (m, i8) in group
    const int g = tid / 192;          // uniform across each wave (192 = 3 waves)
    const int r = tid - g * 192;

    float acc[8];
    int m = 0, i8 = 0;
    if (r < 184) {
        m  = r % 23;
        i8 = r / 23;
        // column j = m + 23a with j%4 == g  ->  a = 3*(g-m) mod 4; col' = (j>>2) + 23g
        int a  = (3 * ((g - m + 8) & 3)) & 3;
        int j  = m + 23 * a;
        int jc = (j >> 2) + 23 * g;
        const unsigned short* colp = &Yt[jc * STR];

        #pragma unroll
        for (int rr = 0; rr < 8; ++rr) acc[rr] = 0.f;

        const int base = i8 * 8;
        for (int rb = 0; rb < 112; rb += 8) {
            uint4 vv = *reinterpret_cast<const uint4*>(&colp[base + rb]);
            float v[8];
            v[0] = bflo(vv.x); v[1] = bfhi(vv.x);
            v[2] = bflo(vv.y); v[3] = bfhi(vv.y);
            v[4] = bflo(vv.z); v[5] = bfhi(vv.z);
            v[6] = bflo(vv.w); v[7] = bfhi(vv.w);
            const float4* wp = reinterpret_cast<const float4*>(&wkp2[g * WKP + rb]);
            float4 w0 = wp[0], w1 = wp[1], w2 = wp[2], w3 = wp[3];
            float wf[16] = { w0.x, w0.y, w0.z, w0.w, w1.x, w1.y, w1.z, w1.w,
                             w2.x, w2.y, w2.z, w2.w, w3.x, w3.y, w3.z, w3.w };
            // acc[rr] (output t0+base+rr) += row(base+rb+k) * wk[h = rb+k-rr], idx = h+7
            #pragma unroll
            for (int k = 0; k < 8; ++k) {
                #pragma unroll
                for (int rr = 0; rr < 8; ++rr)
                    acc[rr] += v[k] * wf[k - rr + 7];
            }
        }
    }
    __syncthreads();   // Yt reads done; arena becomes partials P[t'][m*4+g]

    if (r < 184) {
        #pragma unroll
        for (int rr = 0; rr < 8; ++rr)
            P[(i8 * 8 + rr) * 92 + m * 4 + g] = acc[rr];
    }
    __syncthreads();

    // --- reduce over g: sub[t'][m] = sum_g P[t'][m][g]
    for (int p = tid; p < TILE * 23; p += 768) {
        int t  = p / 23;
        int mm = p - t * 23;
        float4 v4 = *reinterpret_cast<const float4*>(&P[t * 92 + mm * 4]);
        sub[t * 24 + mm] = v4.x + v4.y + v4.z + v4.w;
    }
    __syncthreads();

    // --- tree cascade, one thread per timestep
    if (tid < TILE) {
        int t = t0 + tid;
        if (t < T_DIM) {
            const float* s = &sub[tid * 24];
            float o[M_DIM];
            #pragma unroll
            for (int mm = 11; mm < 23; ++mm) {
                float x = s[mm] - sTheta[mm];
                o[mm] = sExpC[mm] / (1.f + __expf(-x));
            }
            #pragma unroll
            for (int rr = 10; rr >= 0; --rr) {
                float x = s[rr] + o[2 * rr + 1] + o[2 * rr + 2] - sTheta[rr];
                o[rr] = sExpC[rr] / (1.f + __expf(-x));
            }
            out[t] = o[0] + Vo[0];
        }
    }
}

extern "C" void kernel_launch(void* const* d_in, const int* in_sizes, int n_in,
                              void* d_out, int out_size, void* d_ws, size_t ws_size,
                              hipStream_t stream) {
    const float* X     = (const float*)d_in[0];
    const float* Vo    = (const float*)d_in[1];
    const float* Tau   = (const float*)d_in[2];
    const float* Delta = (const float*)d_in[3];
    const float* W     = (const float*)d_in[4];
    const float* C     = (const float*)d_in[5];
    const float* Theta = (const float*)d_in[6];
    float* out = (float*)d_out;
    unsigned short* Yb = (unsigned short*)d_ws;   // T_DIM * 92 bf16 = 5.52 MB

    reduce_k<<<T_DIM / RROWS, 256, 0, stream>>>(X, Yb);
    conv_tree_k<<<(T_DIM + TILE - 1) / TILE, 768, 0, stream>>>(
        Yb, Vo, Tau, Delta, W, C, Theta, out);
}